// Round 3
// baseline (199.919 us; speedup 1.0000x reference)
//
#include <hip/hip_runtime.h>
#include <hip/hip_bf16.h>

// Problem constants
#define S_LEN   4096
#define D_MOD   512
#define BATCH   4
#define HALF_W  128
#define M_TOT   (BATCH * S_LEN)   // 16384

typedef __attribute__((ext_vector_type(8))) short bf16x8;
typedef __attribute__((ext_vector_type(4))) float f32x4;

__device__ __forceinline__ unsigned short f2bf(float f) {
    // round-to-nearest-even bf16 (values are finite here)
    unsigned int u = __float_as_uint(f);
    unsigned int r = (u + 0x7fffu + ((u >> 16) & 1u)) >> 16;
    return (unsigned short)r;
}

__device__ __forceinline__ void async_copy16(const void* g, void* l) {
    __builtin_amdgcn_global_load_lds(
        (const __attribute__((address_space(1))) void*)g,
        (__attribute__((address_space(3))) void*)l, 16, 0, 0);
}

// ---------------------------------------------------------------------------
// Kernel 1: fused converts. Blocks [0,8192): x fp32 -> bf16 (r1-verbatim body).
// Blocks [8192,8384): W[k][n] -> Wt[n][k] bf16 via LDS transpose (r7 body).
__global__ __launch_bounds__(256) void convert_xw(const float* __restrict__ x,
                                                  const float* __restrict__ Wq,
                                                  const float* __restrict__ Wk,
                                                  const float* __restrict__ Wv,
                                                  unsigned short* __restrict__ xb,
                                                  unsigned short* __restrict__ Wt) {
    __shared__ float sT[64][65];
    const int t = threadIdx.x;
    const int bid = blockIdx.x;
    if (bid < 8192) {
        int i = (bid * 256 + t) * 4;
        float4 v = *(const float4*)(x + i);
        ushort4 o;
        o.x = f2bf(v.x); o.y = f2bf(v.y); o.z = f2bf(v.z); o.w = f2bf(v.w);
        *(ushort4*)(xb + i) = o;
        return;
    }
    const int j = bid - 8192;            // 0..191
    const int w = j >> 6;                // weight select (64 tiles each)
    const int rj = j & 63;
    const float* W = (w == 0) ? Wq : ((w == 1) ? Wk : Wv);
    const int n0 = (rj & 7) * 64, k0 = (rj >> 3) * 64;
    const int r = t >> 4, c4 = (t & 15) * 4;
    #pragma unroll
    for (int i = 0; i < 4; ++i) {
        float4 v = *(const float4*)(W + (size_t)(k0 + r + i * 16) * 512 + n0 + c4);
        sT[c4 + 0][r + i * 16] = v.x;
        sT[c4 + 1][r + i * 16] = v.y;
        sT[c4 + 2][r + i * 16] = v.z;
        sT[c4 + 3][r + i * 16] = v.w;
    }
    __syncthreads();
    #pragma unroll
    for (int i = 0; i < 4; ++i) {
        int rr = (t >> 4) + i * 16;   // n-local
        ushort4 o;
        o.x = f2bf(sT[rr][c4 + 0]);
        o.y = f2bf(sT[rr][c4 + 1]);
        o.z = f2bf(sT[rr][c4 + 2]);
        o.w = f2bf(sT[rr][c4 + 3]);
        *(ushort4*)(Wt + (size_t)w * 262144 + (size_t)(n0 + rr) * 512 + k0 + c4) = o;
    }
}

// ---------------------------------------------------------------------------
// Kernel 2: fused QKV GEMM (r9-passing structure + XCD swizzle) with
// bank-conflict-free LDS (byte-identical this round).
__global__ __launch_bounds__(256) void qkv_gemm(
    const unsigned short* __restrict__ xb, const unsigned short* __restrict__ Wt,
    const float* __restrict__ bq, const float* __restrict__ bk, const float* __restrict__ bv,
    unsigned short* __restrict__ Qo, unsigned short* __restrict__ Ko,
    unsigned short* __restrict__ Vt) {
    __shared__ __align__(16) char gsmem[34816];
    unsigned short* sA = (unsigned short*)gsmem;            // [128][64], chunk-swizzled
    unsigned short* sB = (unsigned short*)(gsmem + 16384);  // [128][64], chunk-swizzled
    unsigned short* sT = (unsigned short*)gsmem;            // [128][136] epilogue

    const int t = threadIdx.x;
    const int p = blockIdx.x;
    const int l = (p & 7) * 192 + (p >> 3);
    const int mi = l / 12;
    const int rzn = l - mi * 12;
    const int wsel = rzn >> 2;
    const int ni = rzn & 3;
    const int m0 = mi * 128;
    const int n0 = ni * 128;
    const unsigned short* Wb = Wt + (size_t)wsel * 262144;

    const int w = t >> 6, lane = t & 63;
    const int wm = (w & 1) * 64, wn = (w >> 1) * 64;
    const int qd = lane >> 4, l16 = lane & 15;

    f32x4 acc[4][4] = {};

    for (int k0 = 0; k0 < 512; k0 += 64) {
        __syncthreads();
        #pragma unroll
        for (int i = 0; i < 4; ++i) {
            int c = i * 256 + t;
            int row = c >> 3, cc = c & 7;
            int g = cc ^ (row & 7);                       // source-chunk permute
            async_copy16(xb + (size_t)(m0 + row) * 512 + k0 + g * 8, sA + c * 8);
            async_copy16(Wb + (size_t)(n0 + row) * 512 + k0 + g * 8, sB + c * 8);
        }
        __syncthreads();
        #pragma unroll
        for (int ks = 0; ks < 2; ++ks) {
            bf16x8 af[4], bfr[4];
            #pragma unroll
            for (int i = 0; i < 4; ++i) {
                int row = wm + i * 16 + l16;
                int ch = (ks * 4 + qd) ^ (row & 7);       // logical chunk ks*4+qd
                af[i] = *(const bf16x8*)(sA + row * 64 + ch * 8);
            }
            #pragma unroll
            for (int j = 0; j < 4; ++j) {
                int row = wn + j * 16 + l16;
                int ch = (ks * 4 + qd) ^ (row & 7);
                bfr[j] = *(const bf16x8*)(sB + row * 64 + ch * 8);
            }
            #pragma unroll
            for (int i = 0; i < 4; ++i)
                #pragma unroll
                for (int j = 0; j < 4; ++j)
                    acc[i][j] = __builtin_amdgcn_mfma_f32_16x16x32_bf16(af[i], bfr[j], acc[i][j], 0, 0, 0);
        }
    }

    const float* bias = (wsel == 0) ? bq : ((wsel == 1) ? bk : bv);
    __syncthreads();   // done reading sA/sB; sT aliases them

    if (wsel < 2) {
        #pragma unroll
        for (int j = 0; j < 4; ++j) {
            int n = wn + j * 16 + l16;
            float bj = bias[n0 + n];
            #pragma unroll
            for (int i = 0; i < 4; ++i) {
                int mb = wm + i * 16 + qd * 4;
                #pragma unroll
                for (int r = 0; r < 4; ++r)
                    sT[(mb + r) * 136 + n] = f2bf(acc[i][j][r] + bj);
            }
        }
        __syncthreads();
        unsigned short* Og = (wsel == 0) ? Qo : Ko;
        #pragma unroll
        for (int i2 = 0; i2 < 4; ++i2)
            #pragma unroll
            for (int i3 = 0; i3 < 2; ++i3) {
                int m = i2 * 32 + (t >> 3);
                int ch = (t & 7) + i3 * 8;
                bf16x8 v = *(const bf16x8*)(sT + m * 136 + ch * 8);
                *(bf16x8*)(Og + (size_t)(m0 + m) * 512 + n0 + ch * 8) = v;
            }
    } else {
        #pragma unroll
        for (int j = 0; j < 4; ++j) {
            int n = wn + j * 16 + l16;
            float bj = bias[n0 + n];
            #pragma unroll
            for (int i = 0; i < 4; ++i) {
                int mb = wm + i * 16 + qd * 4;
                #pragma unroll
                for (int r = 0; r < 4; ++r)
                    sT[n * 136 + mb + r] = f2bf(acc[i][j][r] + bj);
            }
        }
        __syncthreads();
        #pragma unroll
        for (int i2 = 0; i2 < 4; ++i2)
            #pragma unroll
            for (int i3 = 0; i3 < 2; ++i3) {
                int n = i2 * 32 + (t >> 3);
                int ch = (t & 7) + i3 * 8;
                bf16x8 v = *(const bf16x8*)(sT + n * 136 + ch * 8);
                *(bf16x8*)(Vt + (size_t)(n0 + n) * M_TOT + m0 + ch * 8) = v;
            }
    }
}

// ---------------------------------------------------------------------------
// Kernel 3: banded attention — v3: producer/consumer wave specialization.
// 512 threads = 8 waves. Waves 0-3 (A): QK^T + softmax -> sP[t&1].
// Waves 4-7 (B): PV of tile t-1 from sP[(t-1)&1] + V, own the O accumulator.
// 2 barriers/tile; all K/V staging reg-staged so barriers never drain vmcnt;
// each global prefetch gets a full iteration (QK ∥ PV) of latency cover.
__global__ __launch_bounds__(512, 2) void attn(const unsigned short* __restrict__ Qg,
                                               const unsigned short* __restrict__ Kg,
                                               const unsigned short* __restrict__ Vt,
                                               float* __restrict__ out) {
    __shared__ __align__(16) unsigned short sK[32 * 520];     // K[32][520]; Q-stage scratch
    __shared__ __align__(16) unsigned short sV[32 * 512];     // V swz [256rp][8chs][8]
    __shared__ __align__(16) unsigned short sP[2][32 * 40];   // P double-buffered (padded)
    __shared__ float lsum[32];

    const int t = threadIdx.x;
    // XCD swizzle: physical p -> logical l = (p&7)*64 + p/8
    const int p = blockIdx.x;
    const int l = (p & 7) * 64 + (p >> 3);
    const int q0 = (l & 127) * 32;       // query offset within batch
    const int b = l >> 7;
    const int bS = b * S_LEN;

    const bool isA = (t < 256);
    const int ta = t & 255;              // index within group
    const int w = (t >> 6) & 3;          // wave index within group (0..3)
    const int lane = t & 63;
    const int qd = lane >> 4, l16 = lane & 15;
    const int qh = (w >> 1) * 16, kh = (w & 1) * 16;   // A-group QK mapping

    if (t < 32) lsum[t] = 0.f;

    // valid key-tile range: key0 = q0-128+32*kt must satisfy 0 <= key0 <= 4064
    const int kt_lo = (q0 < 128) ? ((128 - q0) >> 5) : 0;
    int kt_hi = (4192 - q0) >> 5;
    if (kt_hi > 8) kt_hi = 8;

    bf16x8 kreg[8], vreg[8], qreg[16];
    f32x4 oacc[16] = {};   // B-group: [c4][qt][dt]

    // ---- prologue global prefetch: K(kt_lo) by A, V(kt_lo) by B
    {
        int key0 = q0 - HALF_W + kt_lo * 32;
        if (isA) {
            #pragma unroll
            for (int i = 0; i < 8; ++i) {
                int c = i * 256 + ta;
                int row = c >> 6, cc = c & 63;
                int rowg = key0 + row;
                rowg = (rowg < 0) ? 0 : ((rowg > S_LEN - 1) ? S_LEN - 1 : rowg);
                kreg[i] = *(const bf16x8*)(Kg + (size_t)(bS + rowg) * 512 + cc * 8);
            }
        } else {
            #pragma unroll
            for (int i = 0; i < 8; ++i) {
                int c = i * 256 + ta;
                int rp = c >> 3, chs = c & 7;
                int ch = chs ^ (rp & 7);
                int d = rp * 2 + (ch >> 2);
                int kc = ch & 3;
                int kk = key0 + kc * 8;
                int koff = (kk >= 0 && kk + 8 <= S_LEN) ? kk : 0;   // clamped, masked via P=0
                vreg[i] = *(const bf16x8*)(Vt + (size_t)d * M_TOT + bS + koff);
            }
        }
    }

    // ---- stage Q [32][512] into sK scratch, then A reads its frags to regs
    #pragma unroll
    for (int i = 0; i < 4; ++i) {
        int c = i * 512 + t;
        int row = c >> 6, cc = c & 63;
        async_copy16(Qg + (size_t)(bS + q0 + row) * 512 + cc * 8, sK + row * 512 + cc * 8);
    }
    asm volatile("s_waitcnt vmcnt(0)" ::: "memory");   // Q staged (also drains prefetch; once)
    __builtin_amdgcn_s_barrier();
    if (isA) {
        #pragma unroll
        for (int c4 = 0; c4 < 4; ++c4)
            #pragma unroll
            for (int kc = 0; kc < 4; ++kc)
                qreg[c4 * 4 + kc] = *(const bf16x8*)(sK + (qh + l16) * 512 + c4 * 128 + kc * 32 + qd * 8);
    }
    asm volatile("s_waitcnt lgkmcnt(0)" ::: "memory");  // qreg reads done before K overwrites sK
    __builtin_amdgcn_s_barrier();

    // ---- main loop: iteration kt does QK(kt) [A] in parallel with PV(kt-1) [B]
    for (int kt = kt_lo; kt <= kt_hi + 1; ++kt) {
        const int key0 = q0 - HALF_W + kt * 32;

        // ===== step 1: LDS publishes + next prefetch =====
        if (isA) {
            if (kt <= kt_hi) {
                // write K(kt) [compiler waits exactly on kreg's vmcnt here]
                #pragma unroll
                for (int i = 0; i < 8; ++i) {
                    int c = i * 256 + ta;
                    int row = c >> 6, cc = c & 63;
                    *(bf16x8*)(sK + row * 520 + cc * 8) = kreg[i];
                }
                if (kt < kt_hi) {   // prefetch K(kt+1)
                    int key0n = key0 + 32;
                    #pragma unroll
                    for (int i = 0; i < 8; ++i) {
                        int c = i * 256 + ta;
                        int row = c >> 6, cc = c & 63;
                        int rowg = key0n + row;
                        rowg = (rowg < 0) ? 0 : ((rowg > S_LEN - 1) ? S_LEN - 1 : rowg);
                        kreg[i] = *(const bf16x8*)(Kg + (size_t)(bS + rowg) * 512 + cc * 8);
                    }
                }
            }
        } else {
            if (kt > kt_lo) {
                // write V(kt-1), source-side swizzled at load time
                #pragma unroll
                for (int i = 0; i < 8; ++i) {
                    int c = i * 256 + ta;
                    *(bf16x8*)(sV + c * 8) = vreg[i];
                }
            }
            if (kt > kt_lo && kt <= kt_hi) {   // prefetch V(kt); V(kt_lo) came from prologue
                #pragma unroll
                for (int i = 0; i < 8; ++i) {
                    int c = i * 256 + ta;
                    int rp = c >> 3, chs = c & 7;
                    int ch = chs ^ (rp & 7);
                    int d = rp * 2 + (ch >> 2);
                    int kc = ch & 3;
                    int kk = key0 + kc * 8;
                    int koff = (kk >= 0 && kk + 8 <= S_LEN) ? kk : 0;
                    vreg[i] = *(const bf16x8*)(Vt + (size_t)d * M_TOT + bS + koff);
                }
            }
        }

        asm volatile("s_waitcnt lgkmcnt(0)" ::: "memory");
        __builtin_amdgcn_s_barrier();   // K(kt), V(kt-1) visible; sP(kt-1) visible

        // ===== step 2: QK(kt) [A] ∥ PV(kt-1) [B] =====
        if (isA) {
            if (kt <= kt_hi) {
                f32x4 sacc = {0.f, 0.f, 0.f, 0.f};
                #pragma unroll
                for (int c4 = 0; c4 < 4; ++c4) {
                    #pragma unroll
                    for (int kc = 0; kc < 4; ++kc) {
                        bf16x8 bk8 = *(const bf16x8*)(sK + (kh + l16) * 520 + c4 * 128 + kc * 32 + qd * 8);
                        sacc = __builtin_amdgcn_mfma_f32_16x16x32_bf16(qreg[c4 * 4 + kc], bk8, sacc, 0, 0, 0);
                    }
                }
                const float scale = 0.04419417382415922f;   // 1/sqrt(512)
                unsigned short* sPt = sP[kt & 1];
                #pragma unroll
                for (int r = 0; r < 4; ++r) {
                    int qi = q0 + qh + qd * 4 + r;
                    int kj = key0 + kh + l16;
                    bool valid = (kj >= 0) && (kj < S_LEN) && (kj >= qi - HALF_W) && (kj <= qi + HALF_W);
                    float p2 = valid ? __expf(sacc[r] * scale) : 0.f;
                    sPt[(qh + qd * 4 + r) * 40 + kh + l16] = f2bf(p2);
                    float s = p2;
                    s += __shfl_xor(s, 1);
                    s += __shfl_xor(s, 2);
                    s += __shfl_xor(s, 4);
                    s += __shfl_xor(s, 8);
                    if (l16 == 0) atomicAdd(&lsum[qh + qd * 4 + r], s);
                }
            }
        } else {
            if (kt > kt_lo) {
                const unsigned short* sPp = sP[(kt - 1) & 1];
                #pragma unroll
                for (int c4 = 0; c4 < 4; ++c4) {
                    #pragma unroll
                    for (int qt = 0; qt < 2; ++qt) {
                        bf16x8 ap = *(const bf16x8*)(sPp + (qt * 16 + l16) * 40 + qd * 8);
                        #pragma unroll
                        for (int dt = 0; dt < 2; ++dt) {
                            int dv = c4 * 128 + w * 32 + dt * 16 + l16;
                            int rp = dv >> 1;
                            int chs = (((dv & 1) << 2) + qd) ^ (rp & 7);
                            bf16x8 bv8 = *(const bf16x8*)(sV + rp * 64 + chs * 8);
                            oacc[c4 * 4 + qt * 2 + dt] =
                                __builtin_amdgcn_mfma_f32_16x16x32_bf16(ap, bv8, oacc[c4 * 4 + qt * 2 + dt], 0, 0, 0);
                        }
                    }
                }
            }
        }

        asm volatile("s_waitcnt lgkmcnt(0)" ::: "memory");
        __builtin_amdgcn_s_barrier();   // tile consumed; buffers reusable; lsum(kt) visible
    }

    // ---- epilogue (B group owns O)
    if (!isA) {
        float inv[2][4];
        #pragma unroll
        for (int qt = 0; qt < 2; ++qt)
            #pragma unroll
            for (int r = 0; r < 4; ++r)
                inv[qt][r] = 1.0f / lsum[qt * 16 + qd * 4 + r];

        #pragma unroll
        for (int c4 = 0; c4 < 4; ++c4)
            #pragma unroll
            for (int qt = 0; qt < 2; ++qt)
                #pragma unroll
                for (int dt = 0; dt < 2; ++dt) {
                    int dv = c4 * 128 + w * 32 + dt * 16 + l16;
                    #pragma unroll
                    for (int r = 0; r < 4; ++r) {
                        int q = qt * 16 + qd * 4 + r;
                        out[(size_t)(bS + q0 + q) * 512 + dv] = oacc[c4 * 4 + qt * 2 + dt][r] * inv[qt][r];
                    }
                }
    }
}

// ---------------------------------------------------------------------------
extern "C" void kernel_launch(void* const* d_in, const int* in_sizes, int n_in,
                              void* d_out, int out_size, void* d_ws, size_t ws_size,
                              hipStream_t stream) {
    const float* x  = (const float*)d_in[0];
    const float* Wq = (const float*)d_in[1];
    const float* bq = (const float*)d_in[2];
    const float* Wk = (const float*)d_in[3];
    const float* bk = (const float*)d_in[4];
    const float* Wv = (const float*)d_in[5];
    const float* bv = (const float*)d_in[6];
    float* out = (float*)d_out;

    char* ws = (char*)d_ws;
    unsigned short* xb = (unsigned short*)(ws);                    // 16 MB
    unsigned short* Wt = (unsigned short*)(ws + 16777216);         // 1.5 MB
    unsigned short* Qb = (unsigned short*)(ws + 18350080);         // 16 MB
    unsigned short* Kb = (unsigned short*)(ws + 35127296);         // 16 MB
    unsigned short* Vt = (unsigned short*)(ws + 51904512);         // 16 MB, [512][16384]

    convert_xw<<<8384, 256, 0, stream>>>(x, Wq, Wk, Wv, xb, Wt);
    qkv_gemm<<<1536, 256, 0, stream>>>(xb, Wt, bq, bk, bv, Qb, Kb, Vt);
    attn<<<512, 512, 0, stream>>>(Qb, Kb, Vt, out);
}

// Round 5
// 163.693 us; speedup vs baseline: 1.2213x; 1.2213x over previous
//
#include <hip/hip_runtime.h>
#include <hip/hip_bf16.h>

// Problem constants
#define S_LEN   4096
#define D_MOD   512
#define BATCH   4
#define HALF_W  128
#define M_TOT   (BATCH * S_LEN)   // 16384

typedef __attribute__((ext_vector_type(8))) short bf16x8;
typedef __attribute__((ext_vector_type(4))) float f32x4;

__device__ __forceinline__ unsigned short f2bf(float f) {
    // round-to-nearest-even bf16 (values are finite here)
    unsigned int u = __float_as_uint(f);
    unsigned int r = (u + 0x7fffu + ((u >> 16) & 1u)) >> 16;
    return (unsigned short)r;
}

__device__ __forceinline__ void async_copy16(const void* g, void* l) {
    __builtin_amdgcn_global_load_lds(
        (const __attribute__((address_space(1))) void*)g,
        (__attribute__((address_space(3))) void*)l, 16, 0, 0);
}

// ---------------------------------------------------------------------------
// Kernel 1: fused converts. Blocks [0,8192): x fp32 -> bf16 (r1-verbatim body).
// Blocks [8192,8384): W[k][n] -> Wt[n][k] bf16 via LDS transpose (r7 body).
__global__ __launch_bounds__(256) void convert_xw(const float* __restrict__ x,
                                                  const float* __restrict__ Wq,
                                                  const float* __restrict__ Wk,
                                                  const float* __restrict__ Wv,
                                                  unsigned short* __restrict__ xb,
                                                  unsigned short* __restrict__ Wt) {
    __shared__ float sT[64][65];
    const int t = threadIdx.x;
    const int bid = blockIdx.x;
    if (bid < 8192) {
        int i = (bid * 256 + t) * 4;
        float4 v = *(const float4*)(x + i);
        ushort4 o;
        o.x = f2bf(v.x); o.y = f2bf(v.y); o.z = f2bf(v.z); o.w = f2bf(v.w);
        *(ushort4*)(xb + i) = o;
        return;
    }
    const int j = bid - 8192;            // 0..191
    const int w = j >> 6;                // weight select (64 tiles each)
    const int rj = j & 63;
    const float* W = (w == 0) ? Wq : ((w == 1) ? Wk : Wv);
    const int n0 = (rj & 7) * 64, k0 = (rj >> 3) * 64;
    const int r = t >> 4, c4 = (t & 15) * 4;
    #pragma unroll
    for (int i = 0; i < 4; ++i) {
        float4 v = *(const float4*)(W + (size_t)(k0 + r + i * 16) * 512 + n0 + c4);
        sT[c4 + 0][r + i * 16] = v.x;
        sT[c4 + 1][r + i * 16] = v.y;
        sT[c4 + 2][r + i * 16] = v.z;
        sT[c4 + 3][r + i * 16] = v.w;
    }
    __syncthreads();
    #pragma unroll
    for (int i = 0; i < 4; ++i) {
        int rr = (t >> 4) + i * 16;   // n-local
        ushort4 o;
        o.x = f2bf(sT[rr][c4 + 0]);
        o.y = f2bf(sT[rr][c4 + 1]);
        o.z = f2bf(sT[rr][c4 + 2]);
        o.w = f2bf(sT[rr][c4 + 3]);
        *(ushort4*)(Wt + (size_t)w * 262144 + (size_t)(n0 + rr) * 512 + k0 + c4) = o;
    }
}

// ---------------------------------------------------------------------------
// Kernel 2: fused QKV GEMM (byte-identical this round).
__global__ __launch_bounds__(256) void qkv_gemm(
    const unsigned short* __restrict__ xb, const unsigned short* __restrict__ Wt,
    const float* __restrict__ bq, const float* __restrict__ bk, const float* __restrict__ bv,
    unsigned short* __restrict__ Qo, unsigned short* __restrict__ Ko,
    unsigned short* __restrict__ Vt) {
    __shared__ __align__(16) char gsmem[34816];
    unsigned short* sA = (unsigned short*)gsmem;            // [128][64], chunk-swizzled
    unsigned short* sB = (unsigned short*)(gsmem + 16384);  // [128][64], chunk-swizzled
    unsigned short* sT = (unsigned short*)gsmem;            // [128][136] epilogue

    const int t = threadIdx.x;
    const int p = blockIdx.x;
    const int l = (p & 7) * 192 + (p >> 3);
    const int mi = l / 12;
    const int rzn = l - mi * 12;
    const int wsel = rzn >> 2;
    const int ni = rzn & 3;
    const int m0 = mi * 128;
    const int n0 = ni * 128;
    const unsigned short* Wb = Wt + (size_t)wsel * 262144;

    const int w = t >> 6, lane = t & 63;
    const int wm = (w & 1) * 64, wn = (w >> 1) * 64;
    const int qd = lane >> 4, l16 = lane & 15;

    f32x4 acc[4][4] = {};

    for (int k0 = 0; k0 < 512; k0 += 64) {
        __syncthreads();
        #pragma unroll
        for (int i = 0; i < 4; ++i) {
            int c = i * 256 + t;
            int row = c >> 3, cc = c & 7;
            int g = cc ^ (row & 7);                       // source-chunk permute
            async_copy16(xb + (size_t)(m0 + row) * 512 + k0 + g * 8, sA + c * 8);
            async_copy16(Wb + (size_t)(n0 + row) * 512 + k0 + g * 8, sB + c * 8);
        }
        __syncthreads();
        #pragma unroll
        for (int ks = 0; ks < 2; ++ks) {
            bf16x8 af[4], bfr[4];
            #pragma unroll
            for (int i = 0; i < 4; ++i) {
                int row = wm + i * 16 + l16;
                int ch = (ks * 4 + qd) ^ (row & 7);       // logical chunk ks*4+qd
                af[i] = *(const bf16x8*)(sA + row * 64 + ch * 8);
            }
            #pragma unroll
            for (int j = 0; j < 4; ++j) {
                int row = wn + j * 16 + l16;
                int ch = (ks * 4 + qd) ^ (row & 7);
                bfr[j] = *(const bf16x8*)(sB + row * 64 + ch * 8);
            }
            #pragma unroll
            for (int i = 0; i < 4; ++i)
                #pragma unroll
                for (int j = 0; j < 4; ++j)
                    acc[i][j] = __builtin_amdgcn_mfma_f32_16x16x32_bf16(af[i], bfr[j], acc[i][j], 0, 0, 0);
        }
    }

    const float* bias = (wsel == 0) ? bq : ((wsel == 1) ? bk : bv);
    __syncthreads();   // done reading sA/sB; sT aliases them

    if (wsel < 2) {
        #pragma unroll
        for (int j = 0; j < 4; ++j) {
            int n = wn + j * 16 + l16;
            float bj = bias[n0 + n];
            #pragma unroll
            for (int i = 0; i < 4; ++i) {
                int mb = wm + i * 16 + qd * 4;
                #pragma unroll
                for (int r = 0; r < 4; ++r)
                    sT[(mb + r) * 136 + n] = f2bf(acc[i][j][r] + bj);
            }
        }
        __syncthreads();
        unsigned short* Og = (wsel == 0) ? Qo : Ko;
        #pragma unroll
        for (int i2 = 0; i2 < 4; ++i2)
            #pragma unroll
            for (int i3 = 0; i3 < 2; ++i3) {
                int m = i2 * 32 + (t >> 3);
                int ch = (t & 7) + i3 * 8;
                bf16x8 v = *(const bf16x8*)(sT + m * 136 + ch * 8);
                *(bf16x8*)(Og + (size_t)(m0 + m) * 512 + n0 + ch * 8) = v;
            }
    } else {
        #pragma unroll
        for (int j = 0; j < 4; ++j) {
            int n = wn + j * 16 + l16;
            float bj = bias[n0 + n];
            #pragma unroll
            for (int i = 0; i < 4; ++i) {
                int mb = wm + i * 16 + qd * 4;
                #pragma unroll
                for (int r = 0; r < 4; ++r)
                    sT[n * 136 + mb + r] = f2bf(acc[i][j][r] + bj);
            }
        }
        __syncthreads();
        #pragma unroll
        for (int i2 = 0; i2 < 4; ++i2)
            #pragma unroll
            for (int i3 = 0; i3 < 2; ++i3) {
                int n = i2 * 32 + (t >> 3);
                int ch = (t & 7) + i3 * 8;
                bf16x8 v = *(const bf16x8*)(sT + n * 136 + ch * 8);
                *(bf16x8*)(Vt + (size_t)(n0 + n) * M_TOT + m0 + ch * 8) = v;
            }
    }
}

// ---------------------------------------------------------------------------
// Kernel 3: banded attention — v4b: 64-row Q tiles (halves K/V restage
// traffic), 256 blocks x 512 threads (1 block/CU, 8 waves), Q in registers,
// K/V double-buffered via global_load_lds (prefetch one full tile ahead),
// 2 barriers/tile.  v4 compile fix: no pointer-array initializers into LDS —
// buffer select via ternary on scalar pointers.
__global__ __launch_bounds__(512, 2) void attn(const unsigned short* __restrict__ Qg,
                                               const unsigned short* __restrict__ Kg,
                                               const unsigned short* __restrict__ Vt,
                                               float* __restrict__ out) {
    // LDS arena (137,472 B):
    //   bufK0 [32][520]  @      0 (33,280)
    //   bufV0 [512][32]s @ 33,280 (32,768)   (chunk-swizzled)
    //   bufK1 [32][520]  @ 66,048 (33,280)
    //   bufV1 [512][32]s @ 99,328 (32,768)
    //   sQ scratch [64][512] @ 66,048 (65,536)  -- overlays buf1, prologue only
    //   sP [64][40]      @132,096 ( 5,120)
    //   lsum[64]         @137,216 (   256)
    __shared__ __align__(16) char smem[137472];
    unsigned short* const bK0 = (unsigned short*)(smem);
    unsigned short* const bK1 = (unsigned short*)(smem + 66048);
    unsigned short* const bV0 = (unsigned short*)(smem + 33280);
    unsigned short* const bV1 = (unsigned short*)(smem + 99328);
    unsigned short* const sQ  = (unsigned short*)(smem + 66048);
    unsigned short* const sP  = (unsigned short*)(smem + 132096);
    float* const lsum = (float*)(smem + 137216);

    const int t = threadIdx.x;
    // XCD swizzle over 256 blocks: l = (p&7)*32 + p/8
    const int p = blockIdx.x;
    const int l = (p & 7) * 32 + (p >> 3);
    const int q0 = (l & 63) * 64;        // query offset within batch
    const int b = l >> 6;
    const int bS = b * S_LEN;

    const int w = t >> 6, lane = t & 63;
    const int qd = lane >> 4, l16 = lane & 15;
    const int qs = w >> 1;               // q-sub 0..3 (16 rows each)
    const int qh = qs * 16;
    const int kh = (w & 1) * 16;         // QK key-half
    const int dh = (w & 1) * 256;        // PV d-half

    if (t < 64) lsum[t] = 0.f;

    // key-tile range: key0 = q0-128+32*kt, need key0 > -32 and key0 < S_LEN
    const int kt_lo = (q0 < 128) ? ((128 - q0) >> 5) : 0;
    int kt_hi = (4192 - q0) >> 5;
    if (kt_hi > 9) kt_hi = 9;

    bf16x8 qreg[16];
    f32x4 oacc[16] = {};   // [dt]

    // ---- prologue: async K,V(kt_lo) -> buf0; Q -> sQ scratch (buf1 area)
    {
        int key0 = q0 - HALF_W + kt_lo * 32;
        #pragma unroll
        for (int i = 0; i < 4; ++i) {
            int c = i * 512 + t;
            int row = c >> 6, cc = c & 63;           // row uniform per wave
            int rowg = key0 + row;
            rowg = (rowg < 0) ? 0 : ((rowg > S_LEN - 1) ? S_LEN - 1 : rowg);
            async_copy16(Kg + (size_t)(bS + rowg) * 512 + cc * 8, bK0 + row * 520 + cc * 8);
        }
        #pragma unroll
        for (int i = 0; i < 4; ++i) {
            int c = i * 512 + t;
            int rp = c >> 3, chs = c & 7;
            int ch = chs ^ (rp & 7);                 // source pre-swizzle
            int d = rp * 2 + (ch >> 2);
            int kc = ch & 3;
            int kk = key0 + kc * 8;
            int koff = (kk >= 0 && kk + 8 <= S_LEN) ? kk : 0;   // clamped, masked via P=0
            async_copy16(Vt + (size_t)d * M_TOT + bS + koff, bV0 + c * 8);
        }
        // Q [64][512], source chunk-swizzled so reg-reads are conflict-free
        #pragma unroll
        for (int i = 0; i < 8; ++i) {
            int c = i * 512 + t;
            int row = c >> 6, cc = c & 63;           // row uniform per wave
            int g = cc ^ (row & 7);
            async_copy16(Qg + (size_t)(bS + q0 + row) * 512 + g * 8, sQ + row * 512 + cc * 8);
        }
    }
    asm volatile("s_waitcnt vmcnt(0)" ::: "memory");
    __builtin_amdgcn_s_barrier();
    // Q fragments to registers (physical chunk = logical ^ (row&7))
    #pragma unroll
    for (int c4 = 0; c4 < 4; ++c4)
        #pragma unroll
        for (int kc = 0; kc < 4; ++kc) {
            int chl = c4 * 16 + kc * 4 + qd;
            int chp = chl ^ (l16 & 7);
            qreg[c4 * 4 + kc] = *(const bf16x8*)(sQ + (qh + l16) * 512 + chp * 8);
        }
    asm volatile("s_waitcnt lgkmcnt(0)" ::: "memory");  // qreg done before buf1 reuse
    __builtin_amdgcn_s_barrier();

    // ---- main loop
    int cur = 0;
    for (int kt = kt_lo; kt <= kt_hi; ++kt, cur ^= 1) {
        const int key0 = q0 - HALF_W + kt * 32;

        // (a) buf[cur] asyncs complete (issued a full tile ago); prior-tile
        //     LDS reads drained; all waves aligned.
        asm volatile("s_waitcnt vmcnt(0) lgkmcnt(0)" ::: "memory");
        __builtin_amdgcn_s_barrier();

        // (b) prefetch tile kt+1 into buf[cur^1] (lands during QK+softmax+PV)
        if (kt < kt_hi) {
            int key0n = key0 + 32;
            unsigned short* dK = cur ? bK0 : bK1;
            unsigned short* dV = cur ? bV0 : bV1;
            #pragma unroll
            for (int i = 0; i < 4; ++i) {
                int c = i * 512 + t;
                int row = c >> 6, cc = c & 63;
                int rowg = key0n + row;
                rowg = (rowg < 0) ? 0 : ((rowg > S_LEN - 1) ? S_LEN - 1 : rowg);
                async_copy16(Kg + (size_t)(bS + rowg) * 512 + cc * 8, dK + row * 520 + cc * 8);
            }
            #pragma unroll
            for (int i = 0; i < 4; ++i) {
                int c = i * 512 + t;
                int rp = c >> 3, chs = c & 7;
                int ch = chs ^ (rp & 7);
                int d = rp * 2 + (ch >> 2);
                int kc = ch & 3;
                int kk = key0n + kc * 8;
                int koff = (kk >= 0 && kk + 8 <= S_LEN) ? kk : 0;
                async_copy16(Vt + (size_t)d * M_TOT + bS + koff, dV + c * 8);
            }
        }

        const unsigned short* sK = cur ? bK1 : bK0;
        const unsigned short* sV = cur ? bV1 : bV0;

        // (c) QK: S[16q][16k-half] over full D
        f32x4 sacc = {0.f, 0.f, 0.f, 0.f};
        #pragma unroll
        for (int c4 = 0; c4 < 4; ++c4) {
            #pragma unroll
            for (int kc = 0; kc < 4; ++kc) {
                bf16x8 bk8 = *(const bf16x8*)(sK + (kh + l16) * 520 + c4 * 128 + kc * 32 + qd * 8);
                sacc = __builtin_amdgcn_mfma_f32_16x16x32_bf16(qreg[c4 * 4 + kc], bk8, sacc, 0, 0, 0);
            }
        }
        // mask + exp + write P + row sums
        const float scale = 0.04419417382415922f;   // 1/sqrt(512)
        #pragma unroll
        for (int r = 0; r < 4; ++r) {
            int qi = q0 + qh + qd * 4 + r;
            int kj = key0 + kh + l16;
            bool valid = (kj >= 0) && (kj < S_LEN) && (kj >= qi - HALF_W) && (kj <= qi + HALF_W);
            float p2 = valid ? __expf(sacc[r] * scale) : 0.f;
            sP[(qh + qd * 4 + r) * 40 + kh + l16] = f2bf(p2);
            float s = p2;
            s += __shfl_xor(s, 1);
            s += __shfl_xor(s, 2);
            s += __shfl_xor(s, 4);
            s += __shfl_xor(s, 8);
            if (l16 == 0) atomicAdd(&lsum[qh + qd * 4 + r], s);
        }

        // (d) sP visible to PV (cross-wave: both key-halves of this q-sub)
        asm volatile("s_waitcnt lgkmcnt(0)" ::: "memory");
        __builtin_amdgcn_s_barrier();

        // (e) PV: O[16q][256d-half] += P . V  (swizzled V reads, conflict-free)
        bf16x8 ap = *(const bf16x8*)(sP + (qh + l16) * 40 + qd * 8);
        #pragma unroll
        for (int dt = 0; dt < 16; ++dt) {
            int dv = dh + dt * 16 + l16;
            int rp = dv >> 1;
            int chs = (((dv & 1) << 2) + qd) ^ (rp & 7);
            bf16x8 bv8 = *(const bf16x8*)(sV + rp * 64 + chs * 8);
            oacc[dt] = __builtin_amdgcn_mfma_f32_16x16x32_bf16(ap, bv8, oacc[dt], 0, 0, 0);
        }
    }

    // ---- epilogue (lsum atomics drained by last (d) barrier; PV local)
    asm volatile("s_waitcnt lgkmcnt(0)" ::: "memory");
    __builtin_amdgcn_s_barrier();

    float inv[4];
    #pragma unroll
    for (int r = 0; r < 4; ++r)
        inv[r] = 1.0f / lsum[qh + qd * 4 + r];

    #pragma unroll
    for (int dt = 0; dt < 16; ++dt) {
        int dv = dh + dt * 16 + l16;
        #pragma unroll
        for (int r = 0; r < 4; ++r) {
            int q = qh + qd * 4 + r;
            out[(size_t)(bS + q0 + q) * 512 + dv] = oacc[dt][r] * inv[r];
        }
    }
}

// ---------------------------------------------------------------------------
extern "C" void kernel_launch(void* const* d_in, const int* in_sizes, int n_in,
                              void* d_out, int out_size, void* d_ws, size_t ws_size,
                              hipStream_t stream) {
    const float* x  = (const float*)d_in[0];
    const float* Wq = (const float*)d_in[1];
    const float* bq = (const float*)d_in[2];
    const float* Wk = (const float*)d_in[3];
    const float* bk = (const float*)d_in[4];
    const float* Wv = (const float*)d_in[5];
    const float* bv = (const float*)d_in[6];
    float* out = (float*)d_out;

    char* ws = (char*)d_ws;
    unsigned short* xb = (unsigned short*)(ws);                    // 16 MB
    unsigned short* Wt = (unsigned short*)(ws + 16777216);         // 1.5 MB
    unsigned short* Qb = (unsigned short*)(ws + 18350080);         // 16 MB
    unsigned short* Kb = (unsigned short*)(ws + 35127296);         // 16 MB
    unsigned short* Vt = (unsigned short*)(ws + 51904512);         // 16 MB, [512][16384]

    convert_xw<<<8384, 256, 0, stream>>>(x, Wq, Wk, Wv, xb, Wt);
    qkv_gemm<<<1536, 256, 0, stream>>>(xb, Wt, bq, bk, bv, Qb, Kb, Vt);
    attn<<<256, 512, 0, stream>>>(Qb, Kb, Vt, out);
}

// Round 6
// 159.864 us; speedup vs baseline: 1.2506x; 1.0240x over previous
//
#include <hip/hip_runtime.h>
#include <hip/hip_bf16.h>

// Problem constants
#define S_LEN   4096
#define D_MOD   512
#define BATCH   4
#define HALF_W  128
#define M_TOT   (BATCH * S_LEN)   // 16384

typedef __attribute__((ext_vector_type(8))) short bf16x8;
typedef __attribute__((ext_vector_type(4))) float f32x4;

__device__ __forceinline__ unsigned short f2bf(float f) {
    // round-to-nearest-even bf16 (values are finite here)
    unsigned int u = __float_as_uint(f);
    unsigned int r = (u + 0x7fffu + ((u >> 16) & 1u)) >> 16;
    return (unsigned short)r;
}

__device__ __forceinline__ void async_copy16(const void* g, void* l) {
    __builtin_amdgcn_global_load_lds(
        (const __attribute__((address_space(1))) void*)g,
        (__attribute__((address_space(3))) void*)l, 16, 0, 0);
}

// ---------------------------------------------------------------------------
// Kernel 1: fused converts. Blocks [0,8192): x fp32 -> bf16 (r1-verbatim body).
// Blocks [8192,8384): W[k][n] -> Wt[n][k] bf16 via LDS transpose (r7 body).
__global__ __launch_bounds__(256) void convert_xw(const float* __restrict__ x,
                                                  const float* __restrict__ Wq,
                                                  const float* __restrict__ Wk,
                                                  const float* __restrict__ Wv,
                                                  unsigned short* __restrict__ xb,
                                                  unsigned short* __restrict__ Wt) {
    __shared__ float sT[64][65];
    const int t = threadIdx.x;
    const int bid = blockIdx.x;
    if (bid < 8192) {
        int i = (bid * 256 + t) * 4;
        float4 v = *(const float4*)(x + i);
        ushort4 o;
        o.x = f2bf(v.x); o.y = f2bf(v.y); o.z = f2bf(v.z); o.w = f2bf(v.w);
        *(ushort4*)(xb + i) = o;
        return;
    }
    const int j = bid - 8192;            // 0..191
    const int w = j >> 6;                // weight select (64 tiles each)
    const int rj = j & 63;
    const float* W = (w == 0) ? Wq : ((w == 1) ? Wk : Wv);
    const int n0 = (rj & 7) * 64, k0 = (rj >> 3) * 64;
    const int r = t >> 4, c4 = (t & 15) * 4;
    #pragma unroll
    for (int i = 0; i < 4; ++i) {
        float4 v = *(const float4*)(W + (size_t)(k0 + r + i * 16) * 512 + n0 + c4);
        sT[c4 + 0][r + i * 16] = v.x;
        sT[c4 + 1][r + i * 16] = v.y;
        sT[c4 + 2][r + i * 16] = v.z;
        sT[c4 + 3][r + i * 16] = v.w;
    }
    __syncthreads();
    #pragma unroll
    for (int i = 0; i < 4; ++i) {
        int rr = (t >> 4) + i * 16;   // n-local
        ushort4 o;
        o.x = f2bf(sT[rr][c4 + 0]);
        o.y = f2bf(sT[rr][c4 + 1]);
        o.z = f2bf(sT[rr][c4 + 2]);
        o.w = f2bf(sT[rr][c4 + 3]);
        *(ushort4*)(Wt + (size_t)w * 262144 + (size_t)(n0 + rr) * 512 + k0 + c4) = o;
    }
}

// ---------------------------------------------------------------------------
// Kernel 2: fused QKV GEMM — v2: 2-phase pipeline (T3-minimum recipe).
// Double-buffered LDS (64 KB, 2 blocks/CU -> grid 1536 = exactly 3 balanced
// rounds). Per K-step: STAGE(next tile -> buf^1) issued FIRST, then
// ds_read+MFMA of current buf, then ONE __syncthreads (its vmcnt(0) drain
// lands after a full compute phase of latency cover). Compute body, chunk
// swizzle, and epilogue are byte-identical to the passing version.
__global__ __launch_bounds__(256) void qkv_gemm(
    const unsigned short* __restrict__ xb, const unsigned short* __restrict__ Wt,
    const float* __restrict__ bq, const float* __restrict__ bk, const float* __restrict__ bv,
    unsigned short* __restrict__ Qo, unsigned short* __restrict__ Ko,
    unsigned short* __restrict__ Vt) {
    __shared__ __align__(16) char gsmem[65536];
    unsigned short* const sA0 = (unsigned short*)gsmem;             // [128][64], chunk-swizzled
    unsigned short* const sB0 = (unsigned short*)(gsmem + 16384);
    unsigned short* const sA1 = (unsigned short*)(gsmem + 32768);
    unsigned short* const sB1 = (unsigned short*)(gsmem + 49152);
    unsigned short* const sT  = (unsigned short*)gsmem;             // [128][136] epilogue alias

    const int t = threadIdx.x;
    const int p = blockIdx.x;
    const int l = (p & 7) * 192 + (p >> 3);
    const int mi = l / 12;
    const int rzn = l - mi * 12;
    const int wsel = rzn >> 2;
    const int ni = rzn & 3;
    const int m0 = mi * 128;
    const int n0 = ni * 128;
    const unsigned short* Wb = Wt + (size_t)wsel * 262144;

    const int w = t >> 6, lane = t & 63;
    const int wm = (w & 1) * 64, wn = (w >> 1) * 64;
    const int qd = lane >> 4, l16 = lane & 15;

    f32x4 acc[4][4] = {};

    // prologue: stage k0=0 into buf0
    #pragma unroll
    for (int i = 0; i < 4; ++i) {
        int c = i * 256 + t;
        int row = c >> 3, cc = c & 7;
        int g = cc ^ (row & 7);                       // source-chunk permute
        async_copy16(xb + (size_t)(m0 + row) * 512 + g * 8, sA0 + c * 8);
        async_copy16(Wb + (size_t)(n0 + row) * 512 + g * 8, sB0 + c * 8);
    }
    __syncthreads();   // buf0 ready (vmcnt(0) drained by syncthreads semantics)

    int cur = 0;
    for (int k0 = 0; k0 < 512; k0 += 64) {
        // (1) stage NEXT K-tile into buf^1 (latency covered by compute below)
        if (k0 + 64 < 512) {
            unsigned short* dA = cur ? sA0 : sA1;
            unsigned short* dB = cur ? sB0 : sB1;
            int k0n = k0 + 64;
            #pragma unroll
            for (int i = 0; i < 4; ++i) {
                int c = i * 256 + t;
                int row = c >> 3, cc = c & 7;
                int g = cc ^ (row & 7);
                async_copy16(xb + (size_t)(m0 + row) * 512 + k0n + g * 8, dA + c * 8);
                async_copy16(Wb + (size_t)(n0 + row) * 512 + k0n + g * 8, dB + c * 8);
            }
        }

        // (2) compute current buf
        const unsigned short* sA = cur ? sA1 : sA0;
        const unsigned short* sB = cur ? sB1 : sB0;
        #pragma unroll
        for (int ks = 0; ks < 2; ++ks) {
            bf16x8 af[4], bfr[4];
            #pragma unroll
            for (int i = 0; i < 4; ++i) {
                int row = wm + i * 16 + l16;
                int ch = (ks * 4 + qd) ^ (row & 7);       // logical chunk ks*4+qd
                af[i] = *(const bf16x8*)(sA + row * 64 + ch * 8);
            }
            #pragma unroll
            for (int j = 0; j < 4; ++j) {
                int row = wn + j * 16 + l16;
                int ch = (ks * 4 + qd) ^ (row & 7);
                bfr[j] = *(const bf16x8*)(sB + row * 64 + ch * 8);
            }
            #pragma unroll
            for (int i = 0; i < 4; ++i)
                #pragma unroll
                for (int j = 0; j < 4; ++j)
                    acc[i][j] = __builtin_amdgcn_mfma_f32_16x16x32_bf16(af[i], bfr[j], acc[i][j], 0, 0, 0);
        }

        // (3) single barrier per step: prefetch arrived (covered), buf reusable
        __syncthreads();
        cur ^= 1;
    }

    const float* bias = (wsel == 0) ? bq : ((wsel == 1) ? bk : bv);
    // loop ended with __syncthreads(); sT alias of buf0 safe

    if (wsel < 2) {
        #pragma unroll
        for (int j = 0; j < 4; ++j) {
            int n = wn + j * 16 + l16;
            float bj = bias[n0 + n];
            #pragma unroll
            for (int i = 0; i < 4; ++i) {
                int mb = wm + i * 16 + qd * 4;
                #pragma unroll
                for (int r = 0; r < 4; ++r)
                    sT[(mb + r) * 136 + n] = f2bf(acc[i][j][r] + bj);
            }
        }
        __syncthreads();
        unsigned short* Og = (wsel == 0) ? Qo : Ko;
        #pragma unroll
        for (int i2 = 0; i2 < 4; ++i2)
            #pragma unroll
            for (int i3 = 0; i3 < 2; ++i3) {
                int m = i2 * 32 + (t >> 3);
                int ch = (t & 7) + i3 * 8;
                bf16x8 v = *(const bf16x8*)(sT + m * 136 + ch * 8);
                *(bf16x8*)(Og + (size_t)(m0 + m) * 512 + n0 + ch * 8) = v;
            }
    } else {
        #pragma unroll
        for (int j = 0; j < 4; ++j) {
            int n = wn + j * 16 + l16;
            float bj = bias[n0 + n];
            #pragma unroll
            for (int i = 0; i < 4; ++i) {
                int mb = wm + i * 16 + qd * 4;
                #pragma unroll
                for (int r = 0; r < 4; ++r)
                    sT[n * 136 + mb + r] = f2bf(acc[i][j][r] + bj);
            }
        }
        __syncthreads();
        #pragma unroll
        for (int i2 = 0; i2 < 4; ++i2)
            #pragma unroll
            for (int i3 = 0; i3 < 2; ++i3) {
                int n = i2 * 32 + (t >> 3);
                int ch = (t & 7) + i3 * 8;
                bf16x8 v = *(const bf16x8*)(sT + n * 136 + ch * 8);
                *(bf16x8*)(Vt + (size_t)(n0 + n) * M_TOT + m0 + ch * 8) = v;
            }
    }
}

// ---------------------------------------------------------------------------
// Kernel 3: banded attention — v4b (byte-identical to the passing version).
__global__ __launch_bounds__(512, 2) void attn(const unsigned short* __restrict__ Qg,
                                               const unsigned short* __restrict__ Kg,
                                               const unsigned short* __restrict__ Vt,
                                               float* __restrict__ out) {
    // LDS arena (137,472 B):
    //   bufK0 [32][520]  @      0 (33,280)
    //   bufV0 [512][32]s @ 33,280 (32,768)   (chunk-swizzled)
    //   bufK1 [32][520]  @ 66,048 (33,280)
    //   bufV1 [512][32]s @ 99,328 (32,768)
    //   sQ scratch [64][512] @ 66,048 (65,536)  -- overlays buf1, prologue only
    //   sP [64][40]      @132,096 ( 5,120)
    //   lsum[64]         @137,216 (   256)
    __shared__ __align__(16) char smem[137472];
    unsigned short* const bK0 = (unsigned short*)(smem);
    unsigned short* const bK1 = (unsigned short*)(smem + 66048);
    unsigned short* const bV0 = (unsigned short*)(smem + 33280);
    unsigned short* const bV1 = (unsigned short*)(smem + 99328);
    unsigned short* const sQ  = (unsigned short*)(smem + 66048);
    unsigned short* const sP  = (unsigned short*)(smem + 132096);
    float* const lsum = (float*)(smem + 137216);

    const int t = threadIdx.x;
    // XCD swizzle over 256 blocks: l = (p&7)*32 + p/8
    const int p = blockIdx.x;
    const int l = (p & 7) * 32 + (p >> 3);
    const int q0 = (l & 63) * 64;        // query offset within batch
    const int b = l >> 6;
    const int bS = b * S_LEN;

    const int w = t >> 6, lane = t & 63;
    const int qd = lane >> 4, l16 = lane & 15;
    const int qs = w >> 1;               // q-sub 0..3 (16 rows each)
    const int qh = qs * 16;
    const int kh = (w & 1) * 16;         // QK key-half
    const int dh = (w & 1) * 256;        // PV d-half

    if (t < 64) lsum[t] = 0.f;

    // key-tile range: key0 = q0-128+32*kt, need key0 > -32 and key0 < S_LEN
    const int kt_lo = (q0 < 128) ? ((128 - q0) >> 5) : 0;
    int kt_hi = (4192 - q0) >> 5;
    if (kt_hi > 9) kt_hi = 9;

    bf16x8 qreg[16];
    f32x4 oacc[16] = {};   // [dt]

    // ---- prologue: async K,V(kt_lo) -> buf0; Q -> sQ scratch (buf1 area)
    {
        int key0 = q0 - HALF_W + kt_lo * 32;
        #pragma unroll
        for (int i = 0; i < 4; ++i) {
            int c = i * 512 + t;
            int row = c >> 6, cc = c & 63;           // row uniform per wave
            int rowg = key0 + row;
            rowg = (rowg < 0) ? 0 : ((rowg > S_LEN - 1) ? S_LEN - 1 : rowg);
            async_copy16(Kg + (size_t)(bS + rowg) * 512 + cc * 8, bK0 + row * 520 + cc * 8);
        }
        #pragma unroll
        for (int i = 0; i < 4; ++i) {
            int c = i * 512 + t;
            int rp = c >> 3, chs = c & 7;
            int ch = chs ^ (rp & 7);                 // source pre-swizzle
            int d = rp * 2 + (ch >> 2);
            int kc = ch & 3;
            int kk = key0 + kc * 8;
            int koff = (kk >= 0 && kk + 8 <= S_LEN) ? kk : 0;   // clamped, masked via P=0
            async_copy16(Vt + (size_t)d * M_TOT + bS + koff, bV0 + c * 8);
        }
        // Q [64][512], source chunk-swizzled so reg-reads are conflict-free
        #pragma unroll
        for (int i = 0; i < 8; ++i) {
            int c = i * 512 + t;
            int row = c >> 6, cc = c & 63;           // row uniform per wave
            int g = cc ^ (row & 7);
            async_copy16(Qg + (size_t)(bS + q0 + row) * 512 + g * 8, sQ + row * 512 + cc * 8);
        }
    }
    asm volatile("s_waitcnt vmcnt(0)" ::: "memory");
    __builtin_amdgcn_s_barrier();
    // Q fragments to registers (physical chunk = logical ^ (row&7))
    #pragma unroll
    for (int c4 = 0; c4 < 4; ++c4)
        #pragma unroll
        for (int kc = 0; kc < 4; ++kc) {
            int chl = c4 * 16 + kc * 4 + qd;
            int chp = chl ^ (l16 & 7);
            qreg[c4 * 4 + kc] = *(const bf16x8*)(sQ + (qh + l16) * 512 + chp * 8);
        }
    asm volatile("s_waitcnt lgkmcnt(0)" ::: "memory");  // qreg done before buf1 reuse
    __builtin_amdgcn_s_barrier();

    // ---- main loop
    int cur = 0;
    for (int kt = kt_lo; kt <= kt_hi; ++kt, cur ^= 1) {
        const int key0 = q0 - HALF_W + kt * 32;

        // (a) buf[cur] asyncs complete (issued a full tile ago); prior-tile
        //     LDS reads drained; all waves aligned.
        asm volatile("s_waitcnt vmcnt(0) lgkmcnt(0)" ::: "memory");
        __builtin_amdgcn_s_barrier();

        // (b) prefetch tile kt+1 into buf[cur^1] (lands during QK+softmax+PV)
        if (kt < kt_hi) {
            int key0n = key0 + 32;
            unsigned short* dK = cur ? bK0 : bK1;
            unsigned short* dV = cur ? bV0 : bV1;
            #pragma unroll
            for (int i = 0; i < 4; ++i) {
                int c = i * 512 + t;
                int row = c >> 6, cc = c & 63;
                int rowg = key0n + row;
                rowg = (rowg < 0) ? 0 : ((rowg > S_LEN - 1) ? S_LEN - 1 : rowg);
                async_copy16(Kg + (size_t)(bS + rowg) * 512 + cc * 8, dK + row * 520 + cc * 8);
            }
            #pragma unroll
            for (int i = 0; i < 4; ++i) {
                int c = i * 512 + t;
                int rp = c >> 3, chs = c & 7;
                int ch = chs ^ (rp & 7);
                int d = rp * 2 + (ch >> 2);
                int kc = ch & 3;
                int kk = key0n + kc * 8;
                int koff = (kk >= 0 && kk + 8 <= S_LEN) ? kk : 0;
                async_copy16(Vt + (size_t)d * M_TOT + bS + koff, dV + c * 8);
            }
        }

        const unsigned short* sK = cur ? bK1 : bK0;
        const unsigned short* sV = cur ? bV1 : bV0;

        // (c) QK: S[16q][16k-half] over full D
        f32x4 sacc = {0.f, 0.f, 0.f, 0.f};
        #pragma unroll
        for (int c4 = 0; c4 < 4; ++c4) {
            #pragma unroll
            for (int kc = 0; kc < 4; ++kc) {
                bf16x8 bk8 = *(const bf16x8*)(sK + (kh + l16) * 520 + c4 * 128 + kc * 32 + qd * 8);
                sacc = __builtin_amdgcn_mfma_f32_16x16x32_bf16(qreg[c4 * 4 + kc], bk8, sacc, 0, 0, 0);
            }
        }
        // mask + exp + write P + row sums
        const float scale = 0.04419417382415922f;   // 1/sqrt(512)
        #pragma unroll
        for (int r = 0; r < 4; ++r) {
            int qi = q0 + qh + qd * 4 + r;
            int kj = key0 + kh + l16;
            bool valid = (kj >= 0) && (kj < S_LEN) && (kj >= qi - HALF_W) && (kj <= qi + HALF_W);
            float p2 = valid ? __expf(sacc[r] * scale) : 0.f;
            sP[(qh + qd * 4 + r) * 40 + kh + l16] = f2bf(p2);
            float s = p2;
            s += __shfl_xor(s, 1);
            s += __shfl_xor(s, 2);
            s += __shfl_xor(s, 4);
            s += __shfl_xor(s, 8);
            if (l16 == 0) atomicAdd(&lsum[qh + qd * 4 + r], s);
        }

        // (d) sP visible to PV (cross-wave: both key-halves of this q-sub)
        asm volatile("s_waitcnt lgkmcnt(0)" ::: "memory");
        __builtin_amdgcn_s_barrier();

        // (e) PV: O[16q][256d-half] += P . V  (swizzled V reads, conflict-free)
        bf16x8 ap = *(const bf16x8*)(sP + (qh + l16) * 40 + qd * 8);
        #pragma unroll
        for (int dt = 0; dt < 16; ++dt) {
            int dv = dh + dt * 16 + l16;
            int rp = dv >> 1;
            int chs = (((dv & 1) << 2) + qd) ^ (rp & 7);
            bf16x8 bv8 = *(const bf16x8*)(sV + rp * 64 + chs * 8);
            oacc[dt] = __builtin_amdgcn_mfma_f32_16x16x32_bf16(ap, bv8, oacc[dt], 0, 0, 0);
        }
    }

    // ---- epilogue (lsum atomics drained by last (d) barrier; PV local)
    asm volatile("s_waitcnt lgkmcnt(0)" ::: "memory");
    __builtin_amdgcn_s_barrier();

    float inv[4];
    #pragma unroll
    for (int r = 0; r < 4; ++r)
        inv[r] = 1.0f / lsum[qh + qd * 4 + r];

    #pragma unroll
    for (int dt = 0; dt < 16; ++dt) {
        int dv = dh + dt * 16 + l16;
        #pragma unroll
        for (int r = 0; r < 4; ++r) {
            int q = qh + qd * 4 + r;
            out[(size_t)(bS + q0 + q) * 512 + dv] = oacc[dt][r] * inv[r];
        }
    }
}

// ---------------------------------------------------------------------------
extern "C" void kernel_launch(void* const* d_in, const int* in_sizes, int n_in,
                              void* d_out, int out_size, void* d_ws, size_t ws_size,
                              hipStream_t stream) {
    const float* x  = (const float*)d_in[0];
    const float* Wq = (const float*)d_in[1];
    const float* bq = (const float*)d_in[2];
    const float* Wk = (const float*)d_in[3];
    const float* bk = (const float*)d_in[4];
    const float* Wv = (const float*)d_in[5];
    const float* bv = (const float*)d_in[6];
    float* out = (float*)d_out;

    char* ws = (char*)d_ws;
    unsigned short* xb = (unsigned short*)(ws);                    // 16 MB
    unsigned short* Wt = (unsigned short*)(ws + 16777216);         // 1.5 MB
    unsigned short* Qb = (unsigned short*)(ws + 18350080);         // 16 MB
    unsigned short* Kb = (unsigned short*)(ws + 35127296);         // 16 MB
    unsigned short* Vt = (unsigned short*)(ws + 51904512);         // 16 MB, [512][16384]

    convert_xw<<<8384, 256, 0, stream>>>(x, Wq, Wk, Wv, xb, Wt);
    qkv_gemm<<<1536, 256, 0, stream>>>(xb, Wt, bq, bk, bv, Qb, Kb, Vt);
    attn<<<256, 512, 0, stream>>>(Qb, Kb, Vt, out);
}

// Round 7
// 157.271 us; speedup vs baseline: 1.2712x; 1.0165x over previous
//
#include <hip/hip_runtime.h>
#include <hip/hip_bf16.h>

// Problem constants
#define S_LEN   4096
#define D_MOD   512
#define BATCH   4
#define HALF_W  128
#define M_TOT   (BATCH * S_LEN)   // 16384

typedef __attribute__((ext_vector_type(8))) short bf16x8;
typedef __attribute__((ext_vector_type(4))) float f32x4;

__device__ __forceinline__ unsigned short f2bf(float f) {
    // round-to-nearest-even bf16 (values are finite here)
    unsigned int u = __float_as_uint(f);
    unsigned int r = (u + 0x7fffu + ((u >> 16) & 1u)) >> 16;
    return (unsigned short)r;
}

__device__ __forceinline__ void async_copy16(const void* g, void* l) {
    __builtin_amdgcn_global_load_lds(
        (const __attribute__((address_space(1))) void*)g,
        (__attribute__((address_space(3))) void*)l, 16, 0, 0);
}

// ---------------------------------------------------------------------------
// Kernel 1: fused converts. Blocks [0,8192): x fp32 -> bf16 (r1-verbatim body).
// Blocks [8192,8384): W[k][n] -> Wt[n][k] bf16 via LDS transpose (r7 body).
__global__ __launch_bounds__(256) void convert_xw(const float* __restrict__ x,
                                                  const float* __restrict__ Wq,
                                                  const float* __restrict__ Wk,
                                                  const float* __restrict__ Wv,
                                                  unsigned short* __restrict__ xb,
                                                  unsigned short* __restrict__ Wt) {
    __shared__ float sT[64][65];
    const int t = threadIdx.x;
    const int bid = blockIdx.x;
    if (bid < 8192) {
        int i = (bid * 256 + t) * 4;
        float4 v = *(const float4*)(x + i);
        ushort4 o;
        o.x = f2bf(v.x); o.y = f2bf(v.y); o.z = f2bf(v.z); o.w = f2bf(v.w);
        *(ushort4*)(xb + i) = o;
        return;
    }
    const int j = bid - 8192;            // 0..191
    const int w = j >> 6;                // weight select (64 tiles each)
    const int rj = j & 63;
    const float* W = (w == 0) ? Wq : ((w == 1) ? Wk : Wv);
    const int n0 = (rj & 7) * 64, k0 = (rj >> 3) * 64;
    const int r = t >> 4, c4 = (t & 15) * 4;
    #pragma unroll
    for (int i = 0; i < 4; ++i) {
        float4 v = *(const float4*)(W + (size_t)(k0 + r + i * 16) * 512 + n0 + c4);
        sT[c4 + 0][r + i * 16] = v.x;
        sT[c4 + 1][r + i * 16] = v.y;
        sT[c4 + 2][r + i * 16] = v.z;
        sT[c4 + 3][r + i * 16] = v.w;
    }
    __syncthreads();
    #pragma unroll
    for (int i = 0; i < 4; ++i) {
        int rr = (t >> 4) + i * 16;   // n-local
        ushort4 o;
        o.x = f2bf(sT[rr][c4 + 0]);
        o.y = f2bf(sT[rr][c4 + 1]);
        o.z = f2bf(sT[rr][c4 + 2]);
        o.w = f2bf(sT[rr][c4 + 3]);
        *(ushort4*)(Wt + (size_t)w * 262144 + (size_t)(n0 + rr) * 512 + k0 + c4) = o;
    }
}

// ---------------------------------------------------------------------------
// Kernel 2: fused QKV GEMM — v3: BM=256 x BN=128 tile, 512 threads (8 waves,
// 64x64 out each), LDS 96 KB double-buffered (1 block/CU), grid 768 = exactly
// 3 balanced rounds.  Per K-step per CU: 256 MFMA vs 128 ds_read_b128 (2:1,
// was 1:1 at 128^2).  2-phase pipeline, chunk swizzle, numerics identical.
__global__ __launch_bounds__(512, 1) void qkv_gemm(
    const unsigned short* __restrict__ xb, const unsigned short* __restrict__ Wt,
    const float* __restrict__ bq, const float* __restrict__ bk, const float* __restrict__ bv,
    unsigned short* __restrict__ Qo, unsigned short* __restrict__ Ko,
    unsigned short* __restrict__ Vt) {
    __shared__ __align__(16) char gsmem[98304];
    unsigned short* const sA0 = (unsigned short*)gsmem;             // [256][64], chunk-swizzled
    unsigned short* const sA1 = (unsigned short*)(gsmem + 32768);
    unsigned short* const sB0 = (unsigned short*)(gsmem + 65536);   // [128][64]
    unsigned short* const sB1 = (unsigned short*)(gsmem + 81920);
    unsigned short* const sT  = (unsigned short*)gsmem;             // epilogue alias

    const int t = threadIdx.x;
    // XCD swizzle over 768 blocks (= 8 * 96)
    const int p = blockIdx.x;
    const int l = (p & 7) * 96 + (p >> 3);
    const int mi = l / 12;               // 0..63
    const int rzn = l - mi * 12;
    const int wsel = rzn >> 2;
    const int ni = rzn & 3;
    const int m0 = mi * 256;
    const int n0 = ni * 128;
    const unsigned short* Wb = Wt + (size_t)wsel * 262144;

    const int w = t >> 6, lane = t & 63;
    const int wm = (w & 3) * 64, wn = (w >> 2) * 64;
    const int qd = lane >> 4, l16 = lane & 15;

    f32x4 acc[4][4] = {};

    // prologue: stage k0=0 into buf0 (A: 4 chunks/thread, B: 2 chunks/thread)
    #pragma unroll
    for (int i = 0; i < 4; ++i) {
        int c = i * 512 + t;
        int row = c >> 3, cc = c & 7;
        int g = cc ^ (row & 7);                       // source-chunk permute
        async_copy16(xb + (size_t)(m0 + row) * 512 + g * 8, sA0 + c * 8);
    }
    #pragma unroll
    for (int i = 0; i < 2; ++i) {
        int c = i * 512 + t;
        int row = c >> 3, cc = c & 7;
        int g = cc ^ (row & 7);
        async_copy16(Wb + (size_t)(n0 + row) * 512 + g * 8, sB0 + c * 8);
    }
    __syncthreads();   // buf0 ready (vmcnt(0) drained by syncthreads semantics)

    int cur = 0;
    for (int k0 = 0; k0 < 512; k0 += 64) {
        // (1) stage NEXT K-tile into buf^1 (latency covered by compute below)
        if (k0 + 64 < 512) {
            unsigned short* dA = cur ? sA0 : sA1;
            unsigned short* dB = cur ? sB0 : sB1;
            int k0n = k0 + 64;
            #pragma unroll
            for (int i = 0; i < 4; ++i) {
                int c = i * 512 + t;
                int row = c >> 3, cc = c & 7;
                int g = cc ^ (row & 7);
                async_copy16(xb + (size_t)(m0 + row) * 512 + k0n + g * 8, dA + c * 8);
            }
            #pragma unroll
            for (int i = 0; i < 2; ++i) {
                int c = i * 512 + t;
                int row = c >> 3, cc = c & 7;
                int g = cc ^ (row & 7);
                async_copy16(Wb + (size_t)(n0 + row) * 512 + k0n + g * 8, dB + c * 8);
            }
        }

        // (2) compute current buf
        const unsigned short* sA = cur ? sA1 : sA0;
        const unsigned short* sB = cur ? sB1 : sB0;
        #pragma unroll
        for (int ks = 0; ks < 2; ++ks) {
            bf16x8 af[4], bfr[4];
            #pragma unroll
            for (int i = 0; i < 4; ++i) {
                int row = wm + i * 16 + l16;
                int ch = (ks * 4 + qd) ^ (row & 7);       // logical chunk ks*4+qd
                af[i] = *(const bf16x8*)(sA + row * 64 + ch * 8);
            }
            #pragma unroll
            for (int j = 0; j < 4; ++j) {
                int row = wn + j * 16 + l16;
                int ch = (ks * 4 + qd) ^ (row & 7);
                bfr[j] = *(const bf16x8*)(sB + row * 64 + ch * 8);
            }
            #pragma unroll
            for (int i = 0; i < 4; ++i)
                #pragma unroll
                for (int j = 0; j < 4; ++j)
                    acc[i][j] = __builtin_amdgcn_mfma_f32_16x16x32_bf16(af[i], bfr[j], acc[i][j], 0, 0, 0);
        }

        // (3) single barrier per step: prefetch arrived (covered), buf reusable
        __syncthreads();
        cur ^= 1;
    }

    const float* bias = (wsel == 0) ? bq : ((wsel == 1) ? bk : bv);
    // loop ended with __syncthreads(); sT alias safe

    if (wsel < 2) {
        // sT[m][n'] rows 256, stride 136 (16B-aligned: 272 B)
        #pragma unroll
        for (int j = 0; j < 4; ++j) {
            int n = wn + j * 16 + l16;
            float bj = bias[n0 + n];
            #pragma unroll
            for (int i = 0; i < 4; ++i) {
                int mb = wm + i * 16 + qd * 4;
                #pragma unroll
                for (int r = 0; r < 4; ++r)
                    sT[(mb + r) * 136 + n] = f2bf(acc[i][j][r] + bj);
            }
        }
        __syncthreads();
        unsigned short* Og = (wsel == 0) ? Qo : Ko;
        #pragma unroll
        for (int i2 = 0; i2 < 4; ++i2)
            #pragma unroll
            for (int i3 = 0; i3 < 2; ++i3) {
                int m = i2 * 64 + (t >> 3);               // 0..255
                int ch = (t & 7) + i3 * 8;                // 0..15
                bf16x8 v = *(const bf16x8*)(sT + m * 136 + ch * 8);
                *(bf16x8*)(Og + (size_t)(m0 + m) * 512 + n0 + ch * 8) = v;
            }
    } else {
        // sT[n][m'] rows 128, stride 264 (16B-aligned: 528 B)
        #pragma unroll
        for (int j = 0; j < 4; ++j) {
            int n = wn + j * 16 + l16;
            float bj = bias[n0 + n];
            #pragma unroll
            for (int i = 0; i < 4; ++i) {
                int mb = wm + i * 16 + qd * 4;
                #pragma unroll
                for (int r = 0; r < 4; ++r)
                    sT[n * 264 + mb + r] = f2bf(acc[i][j][r] + bj);
            }
        }
        __syncthreads();
        #pragma unroll
        for (int i2 = 0; i2 < 2; ++i2)
            #pragma unroll
            for (int i3 = 0; i3 < 4; ++i3) {
                int n = i2 * 64 + (t >> 3);               // 0..127
                int ch = (t & 7) + i3 * 8;                // 0..31
                bf16x8 v = *(const bf16x8*)(sT + n * 264 + ch * 8);
                *(bf16x8*)(Vt + (size_t)(n0 + n) * M_TOT + m0 + ch * 8) = v;
            }
    }
}

// ---------------------------------------------------------------------------
// Kernel 3: banded attention — v4b (byte-identical to the passing version).
__global__ __launch_bounds__(512, 2) void attn(const unsigned short* __restrict__ Qg,
                                               const unsigned short* __restrict__ Kg,
                                               const unsigned short* __restrict__ Vt,
                                               float* __restrict__ out) {
    // LDS arena (137,472 B):
    //   bufK0 [32][520]  @      0 (33,280)
    //   bufV0 [512][32]s @ 33,280 (32,768)   (chunk-swizzled)
    //   bufK1 [32][520]  @ 66,048 (33,280)
    //   bufV1 [512][32]s @ 99,328 (32,768)
    //   sQ scratch [64][512] @ 66,048 (65,536)  -- overlays buf1, prologue only
    //   sP [64][40]      @132,096 ( 5,120)
    //   lsum[64]         @137,216 (   256)
    __shared__ __align__(16) char smem[137472];
    unsigned short* const bK0 = (unsigned short*)(smem);
    unsigned short* const bK1 = (unsigned short*)(smem + 66048);
    unsigned short* const bV0 = (unsigned short*)(smem + 33280);
    unsigned short* const bV1 = (unsigned short*)(smem + 99328);
    unsigned short* const sQ  = (unsigned short*)(smem + 66048);
    unsigned short* const sP  = (unsigned short*)(smem + 132096);
    float* const lsum = (float*)(smem + 137216);

    const int t = threadIdx.x;
    // XCD swizzle over 256 blocks: l = (p&7)*32 + p/8
    const int p = blockIdx.x;
    const int l = (p & 7) * 32 + (p >> 3);
    const int q0 = (l & 63) * 64;        // query offset within batch
    const int b = l >> 6;
    const int bS = b * S_LEN;

    const int w = t >> 6, lane = t & 63;
    const int qd = lane >> 4, l16 = lane & 15;
    const int qs = w >> 1;               // q-sub 0..3 (16 rows each)
    const int qh = qs * 16;
    const int kh = (w & 1) * 16;         // QK key-half
    const int dh = (w & 1) * 256;        // PV d-half

    if (t < 64) lsum[t] = 0.f;

    // key-tile range: key0 = q0-128+32*kt, need key0 > -32 and key0 < S_LEN
    const int kt_lo = (q0 < 128) ? ((128 - q0) >> 5) : 0;
    int kt_hi = (4192 - q0) >> 5;
    if (kt_hi > 9) kt_hi = 9;

    bf16x8 qreg[16];
    f32x4 oacc[16] = {};   // [dt]

    // ---- prologue: async K,V(kt_lo) -> buf0; Q -> sQ scratch (buf1 area)
    {
        int key0 = q0 - HALF_W + kt_lo * 32;
        #pragma unroll
        for (int i = 0; i < 4; ++i) {
            int c = i * 512 + t;
            int row = c >> 6, cc = c & 63;           // row uniform per wave
            int rowg = key0 + row;
            rowg = (rowg < 0) ? 0 : ((rowg > S_LEN - 1) ? S_LEN - 1 : rowg);
            async_copy16(Kg + (size_t)(bS + rowg) * 512 + cc * 8, bK0 + row * 520 + cc * 8);
        }
        #pragma unroll
        for (int i = 0; i < 4; ++i) {
            int c = i * 512 + t;
            int rp = c >> 3, chs = c & 7;
            int ch = chs ^ (rp & 7);                 // source pre-swizzle
            int d = rp * 2 + (ch >> 2);
            int kc = ch & 3;
            int kk = key0 + kc * 8;
            int koff = (kk >= 0 && kk + 8 <= S_LEN) ? kk : 0;   // clamped, masked via P=0
            async_copy16(Vt + (size_t)d * M_TOT + bS + koff, bV0 + c * 8);
        }
        // Q [64][512], source chunk-swizzled so reg-reads are conflict-free
        #pragma unroll
        for (int i = 0; i < 8; ++i) {
            int c = i * 512 + t;
            int row = c >> 6, cc = c & 63;           // row uniform per wave
            int g = cc ^ (row & 7);
            async_copy16(Qg + (size_t)(bS + q0 + row) * 512 + g * 8, sQ + row * 512 + cc * 8);
        }
    }
    asm volatile("s_waitcnt vmcnt(0)" ::: "memory");
    __builtin_amdgcn_s_barrier();
    // Q fragments to registers (physical chunk = logical ^ (row&7))
    #pragma unroll
    for (int c4 = 0; c4 < 4; ++c4)
        #pragma unroll
        for (int kc = 0; kc < 4; ++kc) {
            int chl = c4 * 16 + kc * 4 + qd;
            int chp = chl ^ (l16 & 7);
            qreg[c4 * 4 + kc] = *(const bf16x8*)(sQ + (qh + l16) * 512 + chp * 8);
        }
    asm volatile("s_waitcnt lgkmcnt(0)" ::: "memory");  // qreg done before buf1 reuse
    __builtin_amdgcn_s_barrier();

    // ---- main loop
    int cur = 0;
    for (int kt = kt_lo; kt <= kt_hi; ++kt, cur ^= 1) {
        const int key0 = q0 - HALF_W + kt * 32;

        // (a) buf[cur] asyncs complete (issued a full tile ago); prior-tile
        //     LDS reads drained; all waves aligned.
        asm volatile("s_waitcnt vmcnt(0) lgkmcnt(0)" ::: "memory");
        __builtin_amdgcn_s_barrier();

        // (b) prefetch tile kt+1 into buf[cur^1] (lands during QK+softmax+PV)
        if (kt < kt_hi) {
            int key0n = key0 + 32;
            unsigned short* dK = cur ? bK0 : bK1;
            unsigned short* dV = cur ? bV0 : bV1;
            #pragma unroll
            for (int i = 0; i < 4; ++i) {
                int c = i * 512 + t;
                int row = c >> 6, cc = c & 63;
                int rowg = key0n + row;
                rowg = (rowg < 0) ? 0 : ((rowg > S_LEN - 1) ? S_LEN - 1 : rowg);
                async_copy16(Kg + (size_t)(bS + rowg) * 512 + cc * 8, dK + row * 520 + cc * 8);
            }
            #pragma unroll
            for (int i = 0; i < 4; ++i) {
                int c = i * 512 + t;
                int rp = c >> 3, chs = c & 7;
                int ch = chs ^ (rp & 7);
                int d = rp * 2 + (ch >> 2);
                int kc = ch & 3;
                int kk = key0n + kc * 8;
                int koff = (kk >= 0 && kk + 8 <= S_LEN) ? kk : 0;
                async_copy16(Vt + (size_t)d * M_TOT + bS + koff, dV + c * 8);
            }
        }

        const unsigned short* sK = cur ? bK1 : bK0;
        const unsigned short* sV = cur ? bV1 : bV0;

        // (c) QK: S[16q][16k-half] over full D
        f32x4 sacc = {0.f, 0.f, 0.f, 0.f};
        #pragma unroll
        for (int c4 = 0; c4 < 4; ++c4) {
            #pragma unroll
            for (int kc = 0; kc < 4; ++kc) {
                bf16x8 bk8 = *(const bf16x8*)(sK + (kh + l16) * 520 + c4 * 128 + kc * 32 + qd * 8);
                sacc = __builtin_amdgcn_mfma_f32_16x16x32_bf16(qreg[c4 * 4 + kc], bk8, sacc, 0, 0, 0);
            }
        }
        // mask + exp + write P + row sums
        const float scale = 0.04419417382415922f;   // 1/sqrt(512)
        #pragma unroll
        for (int r = 0; r < 4; ++r) {
            int qi = q0 + qh + qd * 4 + r;
            int kj = key0 + kh + l16;
            bool valid = (kj >= 0) && (kj < S_LEN) && (kj >= qi - HALF_W) && (kj <= qi + HALF_W);
            float p2 = valid ? __expf(sacc[r] * scale) : 0.f;
            sP[(qh + qd * 4 + r) * 40 + kh + l16] = f2bf(p2);
            float s = p2;
            s += __shfl_xor(s, 1);
            s += __shfl_xor(s, 2);
            s += __shfl_xor(s, 4);
            s += __shfl_xor(s, 8);
            if (l16 == 0) atomicAdd(&lsum[qh + qd * 4 + r], s);
        }

        // (d) sP visible to PV (cross-wave: both key-halves of this q-sub)
        asm volatile("s_waitcnt lgkmcnt(0)" ::: "memory");
        __builtin_amdgcn_s_barrier();

        // (e) PV: O[16q][256d-half] += P . V  (swizzled V reads, conflict-free)
        bf16x8 ap = *(const bf16x8*)(sP + (qh + l16) * 40 + qd * 8);
        #pragma unroll
        for (int dt = 0; dt < 16; ++dt) {
            int dv = dh + dt * 16 + l16;
            int rp = dv >> 1;
            int chs = (((dv & 1) << 2) + qd) ^ (rp & 7);
            bf16x8 bv8 = *(const bf16x8*)(sV + rp * 64 + chs * 8);
            oacc[dt] = __builtin_amdgcn_mfma_f32_16x16x32_bf16(ap, bv8, oacc[dt], 0, 0, 0);
        }
    }

    // ---- epilogue (lsum atomics drained by last (d) barrier; PV local)
    asm volatile("s_waitcnt lgkmcnt(0)" ::: "memory");
    __builtin_amdgcn_s_barrier();

    float inv[4];
    #pragma unroll
    for (int r = 0; r < 4; ++r)
        inv[r] = 1.0f / lsum[qh + qd * 4 + r];

    #pragma unroll
    for (int dt = 0; dt < 16; ++dt) {
        int dv = dh + dt * 16 + l16;
        #pragma unroll
        for (int r = 0; r < 4; ++r) {
            int q = qh + qd * 4 + r;
            out[(size_t)(bS + q0 + q) * 512 + dv] = oacc[dt][r] * inv[r];
        }
    }
}

// ---------------------------------------------------------------------------
extern "C" void kernel_launch(void* const* d_in, const int* in_sizes, int n_in,
                              void* d_out, int out_size, void* d_ws, size_t ws_size,
                              hipStream_t stream) {
    const float* x  = (const float*)d_in[0];
    const float* Wq = (const float*)d_in[1];
    const float* bq = (const float*)d_in[2];
    const float* Wk = (const float*)d_in[3];
    const float* bk = (const float*)d_in[4];
    const float* Wv = (const float*)d_in[5];
    const float* bv = (const float*)d_in[6];
    float* out = (float*)d_out;

    char* ws = (char*)d_ws;
    unsigned short* xb = (unsigned short*)(ws);                    // 16 MB
    unsigned short* Wt = (unsigned short*)(ws + 16777216);         // 1.5 MB
    unsigned short* Qb = (unsigned short*)(ws + 18350080);         // 16 MB
    unsigned short* Kb = (unsigned short*)(ws + 35127296);         // 16 MB
    unsigned short* Vt = (unsigned short*)(ws + 51904512);         // 16 MB, [512][16384]

    convert_xw<<<8384, 256, 0, stream>>>(x, Wq, Wk, Wv, xb, Wt);
    qkv_gemm<<<768, 512, 0, stream>>>(xb, Wt, bq, bk, bv, Qb, Kb, Vt);
    attn<<<256, 512, 0, stream>>>(Qb, Kb, Vt, out);
}